// Round 1
// baseline (329.867 us; speedup 1.0000x reference)
//
#include <hip/hip_runtime.h>
#include <cstdint>
#include <cstddef>

#define NN 50000
#define FF 128
#define CC 128
#define KK 10

constexpr int TILES_P = NN / 16;            // 3125 row-tiles per protein (50000 % 16 == 0)
constexpr size_t NC = (size_t)NN * CC;      // 6.4M elements per protein output

typedef __bf16 bf16x8 __attribute__((ext_vector_type(8)));
typedef float  f32x4  __attribute__((ext_vector_type(4)));

__device__ __forceinline__ unsigned short f2bf(float f) {
  union { float f; unsigned u; } x; x.f = f;
  unsigned r = x.u + 0x7fffu + ((x.u >> 16) & 1u);   // RNE
  return (unsigned short)(r >> 16);
}
__device__ __forceinline__ float bf2f(unsigned short u) {
  union { unsigned u; float f; } x; x.u = ((unsigned)u) << 16; return x.f;
}

// ---------------------------------------------------------------------------
// Phase 1: S = Z@Wsv -> out (f32); Rs = Z@Wsr, Rd = Z@Wdr -> ws tables (bf16).
// Each wave owns a 32-col slice of all 3 weight matrices in registers
// (24 x bf16x8 = 96 VGPR), grid-strides over 16-row tiles of Z.
// MFMA 16x16x32 bf16; A and B use the SAME k<->(lanegroup,elem) formula, so
// any consistent k-permutation contracts correctly. C/D: col=lane&15,
// row=(lane>>4)*4+reg (m89-verified).
// ---------------------------------------------------------------------------
__global__ __launch_bounds__(256, 2)
void gemm3_kernel(const float* __restrict__ Z1, const float* __restrict__ Z2,
                  const float* __restrict__ Wsv, const float* __restrict__ Wsr,
                  const float* __restrict__ Wdr,
                  float* __restrict__ out, unsigned short* __restrict__ tbl,
                  int p_start, int p_count)
{
  const int tid  = threadIdx.x;
  const int wave = tid >> 6;
  const int lane = tid & 63;
  const int l15  = lane & 15;
  const int lg   = lane >> 4;
  const int col0 = wave * 32;

  const float* Wm[3] = { Wsv, Wsr, Wdr };
  bf16x8 b[3][2][4];
#pragma unroll
  for (int m = 0; m < 3; ++m) {
    const float* __restrict__ W = Wm[m];
#pragma unroll
    for (int j = 0; j < 2; ++j) {
      const int col = col0 + j * 16 + l15;
#pragma unroll
      for (int s = 0; s < 4; ++s) {
        bf16x8 f;
#pragma unroll
        for (int e = 0; e < 8; ++e) {
          const int k = s * 32 + (e >> 2) * 16 + lg * 4 + (e & 3);
          f[e] = (__bf16)W[k * CC + col];
        }
        b[m][j][s] = f;
      }
    }
  }

  const int total = TILES_P * p_count;
  for (int t = blockIdx.x; t < total; t += gridDim.x) {
    const int p_rel = t / TILES_P;
    const int p     = p_start + p_rel;
    const int row0  = (t - p_rel * TILES_P) * 16;
    const float* __restrict__ Z = (p == 0) ? Z1 : Z2;
    const float* zrow = Z + (size_t)(row0 + l15) * FF;

    bf16x8 a[4];
#pragma unroll
    for (int s = 0; s < 4; ++s) {
      const f32x4 ha = *(const f32x4*)(zrow + s * 32 + lg * 4);
      const f32x4 hb = *(const f32x4*)(zrow + s * 32 + 16 + lg * 4);
      bf16x8 f;
      f[0] = (__bf16)ha.x; f[1] = (__bf16)ha.y; f[2] = (__bf16)ha.z; f[3] = (__bf16)ha.w;
      f[4] = (__bf16)hb.x; f[5] = (__bf16)hb.y; f[6] = (__bf16)hb.z; f[7] = (__bf16)hb.w;
      a[s] = f;
    }

    f32x4 acc[3][2] = {};
#pragma unroll
    for (int s = 0; s < 4; ++s)
#pragma unroll
      for (int m = 0; m < 3; ++m)
#pragma unroll
        for (int j = 0; j < 2; ++j)
          acc[m][j] = __builtin_amdgcn_mfma_f32_16x16x32_bf16(a[s], b[m][j][s], acc[m][j], 0, 0, 0);

    float*          outp = out + (size_t)p * NC;
    unsigned short* tRs  = tbl + (size_t)(2 * p_rel + 0) * NC;
    unsigned short* tRd  = tbl + (size_t)(2 * p_rel + 1) * NC;
#pragma unroll
    for (int j = 0; j < 2; ++j) {
      const int col = col0 + j * 16 + l15;
#pragma unroll
      for (int r = 0; r < 4; ++r) {
        const int row = row0 + lg * 4 + r;
        const size_t o = (size_t)row * CC + col;
        outp[o] = acc[0][j][r];
        tRs[o]  = f2bf(acc[1][j][r]);
        tRd[o]  = f2bf(acc[2][j][r]);
      }
    }
  }
}

// ---------------------------------------------------------------------------
// Phase 2: per node, masked-mean gather of Rs/Rd rows (bf16, 256B/row,
// contiguous across the node's 128 threads), add S (in d_out), ReLU in place.
// ---------------------------------------------------------------------------
__global__ __launch_bounds__(256)
void agg_kernel(const int* __restrict__ same1, const int* __restrict__ diff1,
                const int* __restrict__ same2, const int* __restrict__ diff2,
                const unsigned short* __restrict__ tbl, float* __restrict__ out,
                int p_start)
{
  const int node  = blockIdx.x * 2 + (threadIdx.x >> 7);
  const int c     = threadIdx.x & 127;
  const int p_rel = blockIdx.y;
  const int p     = p_start + p_rel;
  const int* __restrict__ same = (p == 0) ? same1 : same2;
  const int* __restrict__ diff = (p == 0) ? diff1 : diff2;
  const unsigned short* __restrict__ tRs = tbl + (size_t)(2 * p_rel + 0) * NC;
  const unsigned short* __restrict__ tRd = tbl + (size_t)(2 * p_rel + 1) * NC;

  float ssum = 0.f, dsum = 0.f;
  int scnt = 0, dcnt = 0;
#pragma unroll
  for (int k = 0; k < KK; ++k) {
    const int is = same[node * KK + k];
    if (is >= 0) { scnt++; ssum += bf2f(tRs[(size_t)is * CC + c]); }
    const int id = diff[node * KK + k];
    if (id >= 0) { dcnt++; dsum += bf2f(tRd[(size_t)id * CC + c]); }
  }
  const size_t o = (size_t)p * NC + (size_t)node * CC + c;
  const float v = out[o] + ssum / (float)(scnt > 0 ? scnt : 1)
                         + dsum / (float)(dcnt > 0 ? dcnt : 1);
  out[o] = v > 0.f ? v : 0.f;
}

// ---------------------------------------------------------------------------
// Safety fallback if ws is too small: direct per-node recompute (slow, correct).
// All branches on neighbor validity are block-uniform (one node per block).
// ---------------------------------------------------------------------------
__global__ __launch_bounds__(128)
void fallback_kernel(const float* __restrict__ Z, const int* __restrict__ same,
                     const int* __restrict__ diff,
                     const float* __restrict__ Wsv, const float* __restrict__ Wsr,
                     const float* __restrict__ Wdr, float* __restrict__ out)
{
  const int node = blockIdx.x;
  const int c    = threadIdx.x;
  __shared__ float zs[FF];
  zs[c] = Z[(size_t)node * FF + c];
  __syncthreads();
  float sig = 0.f;
  for (int f = 0; f < FF; ++f) sig += zs[f] * Wsv[f * CC + c];

  float ssum = 0.f, dsum = 0.f;
  int scnt = 0, dcnt = 0;
  for (int k = 0; k < KK; ++k) {
    const int is = same[node * KK + k];
    if (is >= 0) {
      __syncthreads();
      zs[c] = Z[(size_t)is * FF + c];
      __syncthreads();
      float a = 0.f;
      for (int f = 0; f < FF; ++f) a += zs[f] * Wsr[f * CC + c];
      ssum += a; scnt++;
    }
  }
  for (int k = 0; k < KK; ++k) {
    const int id = diff[node * KK + k];
    if (id >= 0) {
      __syncthreads();
      zs[c] = Z[(size_t)id * FF + c];
      __syncthreads();
      float a = 0.f;
      for (int f = 0; f < FF; ++f) a += zs[f] * Wdr[f * CC + c];
      dsum += a; dcnt++;
    }
  }
  const float v = sig + ssum / (float)(scnt > 0 ? scnt : 1)
                      + dsum / (float)(dcnt > 0 ? dcnt : 1);
  out[(size_t)node * CC + c] = v > 0.f ? v : 0.f;
}

extern "C" void kernel_launch(void* const* d_in, const int* in_sizes, int n_in,
                              void* d_out, int out_size, void* d_ws, size_t ws_size,
                              hipStream_t stream)
{
  const float* Z1    = (const float*)d_in[0];
  const int*   same1 = (const int*)  d_in[1];
  const int*   diff1 = (const int*)  d_in[2];
  const float* Z2    = (const float*)d_in[3];
  const int*   same2 = (const int*)  d_in[4];
  const int*   diff2 = (const int*)  d_in[5];
  const float* Wsv   = (const float*)d_in[6];
  const float* Wsr   = (const float*)d_in[7];
  const float* Wdr   = (const float*)d_in[8];
  float* out = (float*)d_out;
  unsigned short* tbl = (unsigned short*)d_ws;

  const size_t need2 = 4 * NC * sizeof(unsigned short);  // 51.2 MB: both proteins
  const size_t need1 = 2 * NC * sizeof(unsigned short);  // 25.6 MB: one protein
  dim3 blk(256);

  if (ws_size >= need2) {
    gemm3_kernel<<<512, blk, 0, stream>>>(Z1, Z2, Wsv, Wsr, Wdr, out, tbl, 0, 2);
    agg_kernel<<<dim3(NN / 2, 2), blk, 0, stream>>>(same1, diff1, same2, diff2, tbl, out, 0);
  } else if (ws_size >= need1) {
    gemm3_kernel<<<512, blk, 0, stream>>>(Z1, Z2, Wsv, Wsr, Wdr, out, tbl, 0, 1);
    agg_kernel<<<dim3(NN / 2, 1), blk, 0, stream>>>(same1, diff1, same2, diff2, tbl, out, 0);
    gemm3_kernel<<<512, blk, 0, stream>>>(Z1, Z2, Wsv, Wsr, Wdr, out, tbl, 1, 1);
    agg_kernel<<<dim3(NN / 2, 1), blk, 0, stream>>>(same1, diff1, same2, diff2, tbl, out, 1);
  } else {
    fallback_kernel<<<NN, 128, 0, stream>>>(Z1, same1, diff1, Wsv, Wsr, Wdr, out);
    fallback_kernel<<<NN, 128, 0, stream>>>(Z2, same2, diff2, Wsv, Wsr, Wdr, out + NC);
  }
}

// Round 2
// 119.049 us; speedup vs baseline: 2.7708x; 2.7708x over previous
//
#include <hip/hip_runtime.h>
#include <cstdint>
#include <cstddef>

#define NN 50000
#define FF 128
#define CC 128
#define KK 10

constexpr int TILES_P = NN / 16;            // 3125 row-tiles per protein (50000 % 16 == 0)
constexpr size_t NC = (size_t)NN * CC;      // 6.4M elements per protein output

typedef __bf16 bf16x8 __attribute__((ext_vector_type(8)));
typedef float  f32x4  __attribute__((ext_vector_type(4)));

__device__ __forceinline__ unsigned short f2bf(float f) {
  union { float f; unsigned u; } x; x.f = f;
  unsigned r = x.u + 0x7fffu + ((x.u >> 16) & 1u);   // RNE
  return (unsigned short)(r >> 16);
}

// ---------------------------------------------------------------------------
// Phase 1: S = Z@Wsv -> out (f32); Rs = Z@Wsr, Rd = Z@Wdr -> ws tables (bf16).
// Each wave owns a 32-col slice of all 3 weight matrices in registers
// (24 x bf16x8 = 96 VGPR), grid-strides over 16-row tiles of Z.
// ---------------------------------------------------------------------------
__global__ __launch_bounds__(256, 2)
void gemm3_kernel(const float* __restrict__ Z1, const float* __restrict__ Z2,
                  const float* __restrict__ Wsv, const float* __restrict__ Wsr,
                  const float* __restrict__ Wdr,
                  float* __restrict__ out, unsigned short* __restrict__ tbl,
                  int p_start, int p_count)
{
  const int tid  = threadIdx.x;
  const int wave = tid >> 6;
  const int lane = tid & 63;
  const int l15  = lane & 15;
  const int lg   = lane >> 4;
  const int col0 = wave * 32;

  const float* Wm[3] = { Wsv, Wsr, Wdr };
  bf16x8 b[3][2][4];
#pragma unroll
  for (int m = 0; m < 3; ++m) {
    const float* __restrict__ W = Wm[m];
#pragma unroll
    for (int j = 0; j < 2; ++j) {
      const int col = col0 + j * 16 + l15;
#pragma unroll
      for (int s = 0; s < 4; ++s) {
        bf16x8 f;
#pragma unroll
        for (int e = 0; e < 8; ++e) {
          const int k = s * 32 + (e >> 2) * 16 + lg * 4 + (e & 3);
          f[e] = (__bf16)W[k * CC + col];
        }
        b[m][j][s] = f;
      }
    }
  }

  const int total = TILES_P * p_count;
  for (int t = blockIdx.x; t < total; t += gridDim.x) {
    const int p_rel = t / TILES_P;
    const int p     = p_start + p_rel;
    const int row0  = (t - p_rel * TILES_P) * 16;
    const float* __restrict__ Z = (p == 0) ? Z1 : Z2;
    const float* zrow = Z + (size_t)(row0 + l15) * FF;

    bf16x8 a[4];
#pragma unroll
    for (int s = 0; s < 4; ++s) {
      const f32x4 ha = *(const f32x4*)(zrow + s * 32 + lg * 4);
      const f32x4 hb = *(const f32x4*)(zrow + s * 32 + 16 + lg * 4);
      bf16x8 f;
      f[0] = (__bf16)ha.x; f[1] = (__bf16)ha.y; f[2] = (__bf16)ha.z; f[3] = (__bf16)ha.w;
      f[4] = (__bf16)hb.x; f[5] = (__bf16)hb.y; f[6] = (__bf16)hb.z; f[7] = (__bf16)hb.w;
      a[s] = f;
    }

    f32x4 acc[3][2] = {};
#pragma unroll
    for (int s = 0; s < 4; ++s)
#pragma unroll
      for (int m = 0; m < 3; ++m)
#pragma unroll
        for (int j = 0; j < 2; ++j)
          acc[m][j] = __builtin_amdgcn_mfma_f32_16x16x32_bf16(a[s], b[m][j][s], acc[m][j], 0, 0, 0);

    float*          outp = out + (size_t)p * NC;
    unsigned short* tRs  = tbl + (size_t)(2 * p_rel + 0) * NC;
    unsigned short* tRd  = tbl + (size_t)(2 * p_rel + 1) * NC;
#pragma unroll
    for (int j = 0; j < 2; ++j) {
      const int col = col0 + j * 16 + l15;
#pragma unroll
      for (int r = 0; r < 4; ++r) {
        const int row = row0 + lg * 4 + r;
        const size_t o = (size_t)row * CC + col;
        outp[o] = acc[0][j][r];
        tRs[o]  = f2bf(acc[1][j][r]);
        tRd[o]  = f2bf(acc[2][j][r]);
      }
    }
  }
}

// ---------------------------------------------------------------------------
// Phase 2: one WAVE per node. Lane covers cols {2*lane, 2*lane+1}.
// Node id forced to SGPR (readfirstlane) so the 20 neighbor indices are
// scalar loads; all 20 row-gathers (dword = ushort2) issued as one batch
// into registers for max memory-level parallelism. Invalid (-1) indices
// clamp to row 0 and the loaded dword is zeroed (uniform select).
// ---------------------------------------------------------------------------
__global__ __launch_bounds__(256)
void agg_kernel(const int* __restrict__ same1, const int* __restrict__ diff1,
                const int* __restrict__ same2, const int* __restrict__ diff2,
                const unsigned short* __restrict__ tbl, float* __restrict__ out,
                int p_start, int p_count)
{
  const int lane = threadIdx.x & 63;
  const int g_v  = blockIdx.x * 4 + (threadIdx.x >> 6);
  const int g    = __builtin_amdgcn_readfirstlane(g_v);   // node id, SGPR
  const int p_rel = g / NN;                               // 0 or 1, scalar
  const int node  = g - p_rel * NN;
  const int p     = p_start + p_rel;
  const int* __restrict__ same = (p == 0) ? same1 : same2;
  const int* __restrict__ diff = (p == 0) ? diff1 : diff2;
  const unsigned short* __restrict__ tRs = tbl + (size_t)(2 * p_rel + 0) * NC;
  const unsigned short* __restrict__ tRd = tbl + (size_t)(2 * p_rel + 1) * NC;

  // scalar index loads
  int idx[2 * KK];
#pragma unroll
  for (int k = 0; k < KK; ++k) {
    idx[k]      = same[node * KK + k];
    idx[KK + k] = diff[node * KK + k];
  }

  // batched gathers: 20 independent dword loads
  unsigned val[2 * KK];
#pragma unroll
  for (int i = 0; i < 2 * KK; ++i) {
    const unsigned short* __restrict__ t = (i < KK) ? tRs : tRd;
    const int ic = idx[i] < 0 ? 0 : idx[i];
    val[i] = *(const unsigned*)(t + (size_t)ic * CC + lane * 2);
  }

  const size_t o = (size_t)p * NC + (size_t)node * CC + (size_t)(lane * 2);
  const float2 s = *(const float2*)(out + o);

  float slo = 0.f, shi = 0.f, dlo = 0.f, dhi = 0.f;
  int scnt = 0, dcnt = 0;
#pragma unroll
  for (int i = 0; i < 2 * KK; ++i) {
    const unsigned u = (idx[i] < 0) ? 0u : val[i];   // uniform select
    union { unsigned u; float f; } lo, hi;
    lo.u = u << 16;
    hi.u = u & 0xFFFF0000u;
    if (i < KK) { scnt += (idx[i] >= 0); slo += lo.f; shi += hi.f; }
    else        { dcnt += (idx[i] >= 0); dlo += lo.f; dhi += hi.f; }
  }

  const float rs = 1.f / (float)(scnt > 0 ? scnt : 1);
  const float rd = 1.f / (float)(dcnt > 0 ? dcnt : 1);
  const float vlo = s.x + slo * rs + dlo * rd;
  const float vhi = s.y + shi * rs + dhi * rd;
  float2 r;
  r.x = vlo > 0.f ? vlo : 0.f;
  r.y = vhi > 0.f ? vhi : 0.f;
  *(float2*)(out + o) = r;
}

// ---------------------------------------------------------------------------
// Safety fallback if ws is too small: direct per-node recompute (slow, correct).
// ---------------------------------------------------------------------------
__global__ __launch_bounds__(128)
void fallback_kernel(const float* __restrict__ Z, const int* __restrict__ same,
                     const int* __restrict__ diff,
                     const float* __restrict__ Wsv, const float* __restrict__ Wsr,
                     const float* __restrict__ Wdr, float* __restrict__ out)
{
  const int node = blockIdx.x;
  const int c    = threadIdx.x;
  __shared__ float zs[FF];
  zs[c] = Z[(size_t)node * FF + c];
  __syncthreads();
  float sig = 0.f;
  for (int f = 0; f < FF; ++f) sig += zs[f] * Wsv[f * CC + c];

  float ssum = 0.f, dsum = 0.f;
  int scnt = 0, dcnt = 0;
  for (int k = 0; k < KK; ++k) {
    const int is = same[node * KK + k];
    if (is >= 0) {
      __syncthreads();
      zs[c] = Z[(size_t)is * FF + c];
      __syncthreads();
      float a = 0.f;
      for (int f = 0; f < FF; ++f) a += zs[f] * Wsr[f * CC + c];
      ssum += a; scnt++;
    }
  }
  for (int k = 0; k < KK; ++k) {
    const int id = diff[node * KK + k];
    if (id >= 0) {
      __syncthreads();
      zs[c] = Z[(size_t)id * FF + c];
      __syncthreads();
      float a = 0.f;
      for (int f = 0; f < FF; ++f) a += zs[f] * Wdr[f * CC + c];
      dsum += a; dcnt++;
    }
  }
  const float v = sig + ssum / (float)(scnt > 0 ? scnt : 1)
                      + dsum / (float)(dcnt > 0 ? dcnt : 1);
  out[(size_t)node * CC + c] = v > 0.f ? v : 0.f;
}

extern "C" void kernel_launch(void* const* d_in, const int* in_sizes, int n_in,
                              void* d_out, int out_size, void* d_ws, size_t ws_size,
                              hipStream_t stream)
{
  const float* Z1    = (const float*)d_in[0];
  const int*   same1 = (const int*)  d_in[1];
  const int*   diff1 = (const int*)  d_in[2];
  const float* Z2    = (const float*)d_in[3];
  const int*   same2 = (const int*)  d_in[4];
  const int*   diff2 = (const int*)  d_in[5];
  const float* Wsv   = (const float*)d_in[6];
  const float* Wsr   = (const float*)d_in[7];
  const float* Wdr   = (const float*)d_in[8];
  float* out = (float*)d_out;
  unsigned short* tbl = (unsigned short*)d_ws;

  const size_t need2 = 4 * NC * sizeof(unsigned short);  // 51.2 MB: both proteins
  const size_t need1 = 2 * NC * sizeof(unsigned short);  // 25.6 MB: one protein
  dim3 blk(256);

  if (ws_size >= need2) {
    gemm3_kernel<<<512, blk, 0, stream>>>(Z1, Z2, Wsv, Wsr, Wdr, out, tbl, 0, 2);
    agg_kernel<<<(2 * NN) / 4, blk, 0, stream>>>(same1, diff1, same2, diff2, tbl, out, 0, 2);
  } else if (ws_size >= need1) {
    gemm3_kernel<<<512, blk, 0, stream>>>(Z1, Z2, Wsv, Wsr, Wdr, out, tbl, 0, 1);
    agg_kernel<<<NN / 4, blk, 0, stream>>>(same1, diff1, same2, diff2, tbl, out, 0, 1);
    gemm3_kernel<<<512, blk, 0, stream>>>(Z1, Z2, Wsv, Wsr, Wdr, out, tbl, 1, 1);
    agg_kernel<<<NN / 4, blk, 0, stream>>>(same1, diff1, same2, diff2, tbl, out, 1, 1);
  } else {
    fallback_kernel<<<NN, 128, 0, stream>>>(Z1, same1, diff1, Wsv, Wsr, Wdr, out);
    fallback_kernel<<<NN, 128, 0, stream>>>(Z2, same2, diff2, Wsv, Wsr, Wdr, out + NC);
  }
}